// Round 1
// 115.736 us; speedup vs baseline: 1.0069x; 1.0069x over previous
//
#include <hip/hip_runtime.h>

// Fully fused 3-level db4 wavedec (periodization) over (B=64, N=4096, F=64) f32.
// v2: float2 per lane (2 adjacent f-columns per thread) -> 8 B/lane loads/stores,
// halving VMEM instruction count and moving the dword streams to the measured
// 8-16 B/lane coalescing sweet spot. Wave layout: lanes 0-31 cover the 32
// f-pairs of tile t, lanes 32-63 cover tile t+1 (two 256 B segments per
// instruction, fully coalesced). XCD-aware block swizzle (512 % 8 == 0, simple
// bijection valid) keeps halo-sharing neighbor blocks on the same XCD L2.
//
// c[k] = sum_j filt[j] * x[(2k+1-j) mod N]  ==  sum_m w[m]*filtR[m],
// where w[m] = x[(2k-6+m) mod N] and filtR[m] = filt[7-m].
//
// Output rows: [0,512)=cA3, [512,1024)=cD3, [1024,2048)=cD2, [2048,4096)=cD1.

__device__ __forceinline__ float2 ld2(const float* p) {
    return *reinterpret_cast<const float2*>(p);
}
__device__ __forceinline__ void st2(float* p, float2 v) {
    *reinterpret_cast<float2*>(p) = v;
}
__device__ __forceinline__ float2 fma2(float2 a, float s, float2 c) {
    c.x = fmaf(a.x, s, c.x);
    c.y = fmaf(a.y, s, c.y);
    return c;
}

__global__ __launch_bounds__(256) void dwt3_fused_v2(
    const float* __restrict__ in,   // (64, 4096, 64)
    float* __restrict__ out)        // (64, 4096, 64)
{
    // reversed filters (filtR[m] = filt[7-m])
    const float LOR[8] = { 0.23037781330885523f,   0.7148465705525415f,
                           0.6308807679295904f,   -0.02798376941698385f,
                          -0.18703481171888114f,   0.030841381835986965f,
                           0.032883011666982945f, -0.010597401784997278f};
    const float HIR[8] = {-0.010597401784997278f, -0.032883011666982945f,
                           0.030841381835986965f,  0.18703481171888114f,
                          -0.02798376941698385f,  -0.6308807679295904f,
                           0.7148465705525415f,   -0.23037781330885523f};

    // XCD-aware swizzle: 512 blocks, 8 XCDs, 64 contiguous blocks per XCD.
    const int bid  = blockIdx.x;
    const int swz  = (bid & 7) * 64 + (bid >> 3);

    const int lane = threadIdx.x & 63;
    const int wv   = threadIdx.x >> 6;             // wave within block (0..3)
    const int f    = (lane & 31) * 2;              // f-pair base column
    const int tsub = lane >> 5;                    // which tile half of the wave
    const int b    = swz >> 3;                     // 64 batches
    const int tile = (swz & 7) * 8 + wv * 2 + tsub; // 64 tiles of T3=8 per batch
    const int K3   = tile * 8;

    const float* inB  = in  + (size_t)b * 4096 * 64 + f;
    float*       outB = out + (size_t)b * 4096 * 64 + f;

    const int i1s = 4 * K3 - 18;   // first level-1 index produced (even)

    float2 w0[8];                  // rolling window x[(2*i1-6 .. 2*i1+1) mod N]
    float2 w1[8];                  // last 8 cA1 values
    float2 w2[8];                  // last 8 cA2 values
    #pragma unroll
    for (int m = 0; m < 8; ++m) {
        w1[m] = make_float2(0.f, 0.f);
        w2[m] = make_float2(0.f, 0.f);
    }

    #pragma unroll
    for (int m = 0; m < 8; ++m) {
        const int r = (2 * i1s - 6 + m) & 4095;
        w0[m] = ld2(inB + (size_t)r * 64);
    }

    #pragma unroll
    for (int s = 0; s < 50; ++s) {
        const int i1 = i1s + s;
        if (s > 0) {
            #pragma unroll
            for (int m = 0; m < 6; ++m) w0[m] = w0[m + 2];
            const int ra = (2 * i1)     & 4095;
            const int rb = (2 * i1 + 1) & 4095;
            w0[6] = ld2(inB + (size_t)ra * 64);
            w0[7] = ld2(inB + (size_t)rb * 64);
        }

        // ---- level 1 ----
        float2 a1 = make_float2(0.f, 0.f);
        #pragma unroll
        for (int m = 0; m < 8; ++m) a1 = fma2(w0[m], LOR[m], a1);
        if (s >= 18) {                       // i1 in own range [4K3, 4K3+32)
            float2 d1 = make_float2(0.f, 0.f);
            #pragma unroll
            for (int m = 0; m < 8; ++m) d1 = fma2(w0[m], HIR[m], d1);
            st2(outB + (size_t)((2048 + i1) & 4095) * 64, d1);
        }
        #pragma unroll
        for (int m = 0; m < 7; ++m) w1[m] = w1[m + 1];
        w1[7] = a1;

        // ---- level 2: emit when i1 = 2*i2+1 (s odd) and window full ----
        if ((s & 1) && s >= 7) {
            const int i2 = 2 * K3 + (s - 19) / 2;   // exact for odd s
            float2 a2 = make_float2(0.f, 0.f);
            #pragma unroll
            for (int m = 0; m < 8; ++m) a2 = fma2(w1[m], LOR[m], a2);
            if (s >= 19) {                   // i2 in own range [2K3, 2K3+16)
                float2 d2 = make_float2(0.f, 0.f);
                #pragma unroll
                for (int m = 0; m < 8; ++m) d2 = fma2(w1[m], HIR[m], d2);
                st2(outB + (size_t)((1024 + i2) & 4095) * 64, d2);
            }
            #pragma unroll
            for (int m = 0; m < 7; ++m) w2[m] = w2[m + 1];
            w2[7] = a2;

            // ---- level 3: emit when i2 = 2*i3+1 and window full ----
            if (s >= 21 && ((s - 21) & 3) == 0) {
                const int i3 = K3 + (s - 21) / 4;    // own range [K3, K3+8)
                float2 a3 = make_float2(0.f, 0.f);
                float2 d3 = make_float2(0.f, 0.f);
                #pragma unroll
                for (int m = 0; m < 8; ++m) {
                    a3 = fma2(w2[m], LOR[m], a3);
                    d3 = fma2(w2[m], HIR[m], d3);
                }
                st2(outB + (size_t)(i3 & 4095) * 64,         a3);
                st2(outB + (size_t)((512 + i3) & 4095) * 64, d3);
            }
        }
    }
}

extern "C" void kernel_launch(void* const* d_in, const int* in_sizes, int n_in,
                              void* d_out, int out_size, void* d_ws, size_t ws_size,
                              hipStream_t stream) {
    (void)in_sizes; (void)n_in; (void)out_size; (void)d_ws; (void)ws_size;
    const float* x = (const float*)d_in[0];
    float* out = (float*)d_out;
    // 64 batches * 8 tile-groups (4 waves/block * 2 tiles/wave) = 512 blocks
    dwt3_fused_v2<<<512, 256, 0, stream>>>(x, out);
}